// Round 1
// baseline (437.826 us; speedup 1.0000x reference)
//
#include <hip/hip_runtime.h>
#include <hip/hip_bf16.h>

#define NNODES 100000
#define NEDGES 1600000
#define KDIM 256
#define ODIM 128
#define NSHARD 16         // counts sharding: 16 counters per node, selected by e&15
#define NB_SCAN 391       // ceil(100000 / 256)
#define EDGE_CAP 1900032  // 1.6M + 3*100000, rounded up a bit
#define ESTRIDE 400000    // NEDGES / 4
#define GEMM_BLOCKS 1563  // ceil(100000 / 64)
#define RANK_BLOCKS 1563  // ceil(400000 / 256)

typedef __attribute__((ext_vector_type(8))) short short8;
typedef __attribute__((ext_vector_type(4))) float floatx4;

// round-to-nearest-even f32 -> bf16 (inputs are finite Gaussians; no NaN handling needed)
static __device__ __forceinline__ short f2bf(float f) {
  union { float f; unsigned u; } x; x.f = f;
  unsigned r = (x.u + 0x7fffu + ((x.u >> 16) & 1u)) >> 16;
  return (short)r;
}

__global__ void conv_w_kernel(const float* __restrict__ W, short* __restrict__ Wb) {
  int i = blockIdx.x * 256 + threadIdx.x;
  if (i < ODIM * KDIM) Wb[i] = f2bf(W[i]);
}

// scan1: one node per thread. Sum the node's 16 shard counts, pad total to
// multiple of 4 (spmm reads int4 pairs), block-level exclusive scan.
__global__ void scan1_kernel(const int* __restrict__ counts, int* __restrict__ chunkExcl,
                             int* __restrict__ blockSums) {
  __shared__ int s[256];
  int t = threadIdx.x;
  int n = blockIdx.x * 256 + t;
  int sum = 0;
  if (n < NNODES) {
    const int4* c4 = (const int4*)(counts + (size_t)n * NSHARD);
    int4 a = c4[0], b = c4[1], c = c4[2], d = c4[3];
    sum = a.x + a.y + a.z + a.w + b.x + b.y + b.z + b.w +
          c.x + c.y + c.z + c.w + d.x + d.y + d.z + d.w;
    sum = (sum + 3) & ~3;  // pad segment to multiple of 4 records
  }
  s[t] = sum;
  __syncthreads();
  for (int o = 1; o < 256; o <<= 1) {
    int add = (t >= o) ? s[t - o] : 0;
    __syncthreads();
    s[t] += add;
    __syncthreads();
  }
  if (n < NNODES) chunkExcl[n] = s[t] - sum;
  if (t == 255) blockSums[blockIdx.x] = s[255];
}

// single-block exclusive scan of the 391 chunk totals; writes offsets[NNODES] = total
__global__ void scan2_kernel(const int* __restrict__ blockSums, int* __restrict__ blockBase,
                             int* __restrict__ offsets) {
  __shared__ int s[512];
  int t = threadIdx.x;
  int v = (t < NB_SCAN) ? blockSums[t] : 0;
  s[t] = v;
  __syncthreads();
  for (int o = 1; o < 512; o <<= 1) {
    int add = (t >= o) ? s[t - o] : 0;
    __syncthreads();
    s[t] += add;
    __syncthreads();
  }
  if (t < NB_SCAN) blockBase[t] = s[t] - v;
  if (t == 511) offsets[NNODES] = s[511];
}

// scan3: per node, write offsets[n] (segment start, multiple of 4) and convert the
// node's 16 shard COUNTS in place into ABSOLUTE shard base positions.
__global__ void scan3_kernel(const int* __restrict__ chunkExcl, const int* __restrict__ blockBase,
                             int* __restrict__ counts, int* __restrict__ offsets) {
  int n = blockIdx.x * 256 + threadIdx.x;
  if (n >= NNODES) return;
  int run = chunkExcl[n] + blockBase[n >> 8];
  offsets[n] = run;
  int4* c4 = (int4*)(counts + (size_t)n * NSHARD);
  int4 q0 = c4[0], q1 = c4[1], q2 = c4[2], q3 = c4[3];
  int4 b0, b1, b2, b3;
  b0.x = run; run += q0.x; b0.y = run; run += q0.y;
  b0.z = run; run += q0.z; b0.w = run; run += q0.w;
  b1.x = run; run += q1.x; b1.y = run; run += q1.y;
  b1.z = run; run += q1.z; b1.w = run; run += q1.w;
  b2.x = run; run += q2.x; b2.y = run; run += q2.y;
  b2.z = run; run += q2.z; b2.w = run; run += q2.w;
  b3.x = run; run += q3.x; b3.y = run; run += q3.y;
  b3.z = run; run += q3.z; b3.w = run; run += q3.w;
  c4[0] = b0; c4[1] = b1; c4[2] = b2; c4[3] = b3;
}

// Atomic-free placement: pos = shardBase[16*r + (e&15)] + rank. sbase is 6.4 MB
// (L2-resident random read); the scattered 8 B store has no RMW dependency.
__global__ void place_kernel(const int* __restrict__ rows, const int* __restrict__ cols,
                             const float* __restrict__ vals,
                             const unsigned short* __restrict__ rank,
                             const int* __restrict__ sbase, int2* __restrict__ edges) {
  int i = blockIdx.x * 256 + threadIdx.x;
#pragma unroll
  for (int j = 0; j < 4; j++) {
    int e = i + j * ESTRIDE;
    if (e < NEDGES) {
      int r = rows[e];
      int p = sbase[(r << 4) | (e & 15)] + (int)rank[e];
      int2 rec;
      rec.x = cols[e];
      rec.y = __float_as_int(vals[e]);
      edges[p] = rec;
    }
  }
}

// Fused: blocks [0, GEMM_BLOCKS) compute packed bf16 H; blocks [GEMM_BLOCKS, +RANK)
// run the sharded histogram+rank atomics (counts[16r + (e&15)] -> ~16 atomics per
// 64B line instead of ~256; contention at the coherence point drops 16x).
//
// gemm: 64 rows/block, 16 rows/wave, all 8 n-tiles per wave. The lane's whole X
// row slice (16 float4) is prefetched up-front -> 16 loads in flight per lane;
// the k-loop then only waits once instead of one L3 round trip per k-step.
// D layout: col = t*16 + (lane&15), row = quad*4 + reg  [m89 layout]
// H is stored PACKED: u32 word j of row = (bf16 col j) | (bf16 col j+64)<<16.
// Cols j and j+64 live in the same lane (acc[t], acc[t+4]) -> lane-local pack,
// 4-byte stores covering full 64 B lines (kills the 2 B scattered-store RFO).
__global__ __launch_bounds__(256) void gemm_rank_kernel(
    const float* __restrict__ X, const short* __restrict__ Wb,
    const float* __restrict__ bias, unsigned* __restrict__ H2,
    const int* __restrict__ rows, int* __restrict__ counts,
    unsigned short* __restrict__ rank) {
  if (blockIdx.x >= GEMM_BLOCKS) {
    // ---- rank path: 4 independent atomic chains per thread, sharded 16-way ----
    int i = (blockIdx.x - GEMM_BLOCKS) * 256 + threadIdx.x;
#pragma unroll
    for (int j = 0; j < 4; j++) {
      int e = i + j * ESTRIDE;
      if (e < NEDGES) {
        int r = rows[e];
        rank[e] = (unsigned short)atomicAdd(&counts[(r << 4) | (e & 15)], 1);
      }
    }
    return;
  }
  // ---- gemm path ----
  const int lane = threadIdx.x & 63;
  const int wave = threadIdx.x >> 6;
  const int l16 = lane & 15;
  const int quad = lane >> 4;
  const int rowBase = blockIdx.x * 64 + wave * 16;
  const int arow = rowBase + l16;
  const bool inb = arow < NNODES;
  const float4 zf4 = {0.f, 0.f, 0.f, 0.f};
  // lane's X stream: row arow, starting at k = quad*8; k-step stride = 32 floats
  const float4* xp = (const float4*)(X + (size_t)(inb ? arow : 0) * KDIM + quad * 8);

  // full-row register prefetch: 16 dwordx4 loads issued before any compute
  float4 xr[16];
#pragma unroll
  for (int k0 = 0; k0 < 8; k0++) {
    xr[2 * k0]     = inb ? xp[k0 * 8]     : zf4;
    xr[2 * k0 + 1] = inb ? xp[k0 * 8 + 1] : zf4;
  }

  floatx4 acc[8];
#pragma unroll
  for (int t = 0; t < 8; t++) acc[t] = (floatx4){0.f, 0.f, 0.f, 0.f};

#pragma unroll
  for (int k0 = 0; k0 < 8; k0++) {
    const float4 c0 = xr[2 * k0];
    const float4 c1 = xr[2 * k0 + 1];
    short8 a;
    a[0] = f2bf(c0.x); a[1] = f2bf(c0.y); a[2] = f2bf(c0.z); a[3] = f2bf(c0.w);
    a[4] = f2bf(c1.x); a[5] = f2bf(c1.y); a[6] = f2bf(c1.z); a[7] = f2bf(c1.w);
    const short* bp = Wb + k0 * 32 + quad * 8;
#pragma unroll
    for (int t = 0; t < 8; t++) {
      short8 b = *(const short8*)(bp + (size_t)(t * 16 + l16) * KDIM);
      acc[t] = __builtin_amdgcn_mfma_f32_16x16x32_bf16(a, b, acc[t], 0, 0, 0);
    }
  }

#pragma unroll
  for (int t = 0; t < 4; t++) {
    const int cl = t * 16 + l16;
    const float blo = bias[cl];
    const float bhi = bias[cl + 64];
#pragma unroll
    for (int r = 0; r < 4; r++) {
      const int row = rowBase + quad * 4 + r;
      if (row < NNODES) {
        unsigned lo = (unsigned short)f2bf(acc[t][r] + blo);
        unsigned hi = (unsigned short)f2bf(acc[t + 4][r] + bhi);
        H2[(size_t)row * 64 + cl] = lo | (hi << 16);
      }
    }
  }
}

// One wave per output row. Lane owns channels {lane, lane+64} (one uint = packed
// bf16 pair per gathered H row -> 256 B coalesced per edge). Segments are padded
// to a multiple of 4 records (pad = {col 0, val 0}) -> no tail loop.
__global__ __launch_bounds__(256) void spmm_kernel(const int* __restrict__ offsets,
                                                   const int2* __restrict__ edges,
                                                   const unsigned* __restrict__ H2,
                                                   float* __restrict__ out) {
  const int lane = threadIdx.x & 63;
  const int row = blockIdx.x * 4 + (threadIdx.x >> 6);
  if (row >= NNODES) return;
  const int s = offsets[row];      // multiple of 4
  const int e = offsets[row + 1];
  float ax = 0.f, ay = 0.f;
  for (int i = s; i < e; i += 4) {
    const int4 p01 = *(const int4*)(edges + i);      // 16 B aligned (s % 4 == 0)
    const int4 p23 = *(const int4*)(edges + i + 2);
    const unsigned h0 = H2[(size_t)p01.x * 64 + lane];
    const unsigned h1 = H2[(size_t)p01.z * 64 + lane];
    const unsigned h2 = H2[(size_t)p23.x * 64 + lane];
    const unsigned h3 = H2[(size_t)p23.z * 64 + lane];
    const float v0 = __int_as_float(p01.y);
    const float v1 = __int_as_float(p01.w);
    const float v2 = __int_as_float(p23.y);
    const float v3 = __int_as_float(p23.w);
    ax += v0 * __uint_as_float(h0 << 16);            // col = lane
    ay += v0 * __uint_as_float(h0 & 0xffff0000u);    // col = lane + 64
    ax += v1 * __uint_as_float(h1 << 16);
    ay += v1 * __uint_as_float(h1 & 0xffff0000u);
    ax += v2 * __uint_as_float(h2 << 16);
    ay += v2 * __uint_as_float(h2 & 0xffff0000u);
    ax += v3 * __uint_as_float(h3 << 16);
    ay += v3 * __uint_as_float(h3 & 0xffff0000u);
  }
  out[(size_t)row * 128 + lane] = ax;
  out[(size_t)row * 128 + 64 + lane] = ay;
}

extern "C" void kernel_launch(void* const* d_in, const int* in_sizes, int n_in,
                              void* d_out, int out_size, void* d_ws, size_t ws_size,
                              hipStream_t stream) {
  const float* X = (const float*)d_in[0];
  const int* erow = (const int*)d_in[1];
  const int* ecol = (const int*)d_in[2];
  const float* eval = (const float*)d_in[3];
  const float* W = (const float*)d_in[4];
  const float* bias = (const float*)d_in[5];
  float* out = (float*)d_out;

  char* ws = (char*)d_ws;
  size_t off = 0;
  auto alloc = [&](size_t bytes) -> char* {
    char* p = ws + off;
    off += (bytes + 255) & ~(size_t)255;
    return p;
  };
  unsigned* Hb = (unsigned*)alloc((size_t)NNODES * 64 * 4);                // 25.6 MB packed
  short* Wb = (short*)alloc((size_t)ODIM * KDIM * 2);                      // 64 KB
  int* counts = (int*)alloc((size_t)NNODES * NSHARD * 4);                  // 6.4 MB (-> bases)
  int* chunkExcl = (int*)alloc((size_t)NNODES * 4);
  int* offsets = (int*)alloc((size_t)(NNODES + 1) * 4);
  int* blockSums = (int*)alloc((size_t)NB_SCAN * 4);
  int* blockBase = (int*)alloc((size_t)NB_SCAN * 4);
  unsigned short* rank = (unsigned short*)alloc((size_t)NEDGES * 2);  // 3.2 MB
  int2* edges = (int2*)alloc((size_t)EDGE_CAP * 8);  // 15.2 MB, padded CSR records

  hipMemsetAsync(counts, 0, (size_t)NNODES * NSHARD * 4, stream);
  hipMemsetAsync(edges, 0, (size_t)EDGE_CAP * 8, stream);  // pad records = {col 0, val 0}
  conv_w_kernel<<<(ODIM * KDIM + 255) / 256, 256, 0, stream>>>(W, Wb);
  gemm_rank_kernel<<<GEMM_BLOCKS + RANK_BLOCKS, 256, 0, stream>>>(X, Wb, bias, Hb,
                                                                 erow, counts, rank);
  scan1_kernel<<<NB_SCAN, 256, 0, stream>>>(counts, chunkExcl, blockSums);
  scan2_kernel<<<1, 512, 0, stream>>>(blockSums, blockBase, offsets);
  scan3_kernel<<<NB_SCAN, 256, 0, stream>>>(chunkExcl, blockBase, counts, offsets);
  place_kernel<<<(ESTRIDE + 255) / 256, 256, 0, stream>>>(erow, ecol, eval, rank, counts, edges);
  spmm_kernel<<<(NNODES + 3) / 4, 256, 0, stream>>>(offsets, edges, (const unsigned*)Hb, out);
}

// Round 2
// 403.682 us; speedup vs baseline: 1.0846x; 1.0846x over previous
//
#include <hip/hip_runtime.h>
#include <hip/hip_bf16.h>

#define NNODES 100000
#define NEDGES 1600000
#define KDIM 256
#define ODIM 128
#define NXCD 8            // counts replicated per-XCD; selected by HW_REG_XCC_ID
#define NB_SCAN 391       // ceil(100000 / 256)
#define EDGE_CAP 1900032  // 1.6M + 3*100000, rounded up a bit
#define ESTRIDE 400000    // NEDGES / 4
#define GEMM_BLOCKS 1563  // ceil(100000 / 64)
#define RANK_BLOCKS 1563  // ceil(400000 / 256)

typedef __attribute__((ext_vector_type(8))) short short8;
typedef __attribute__((ext_vector_type(4))) float floatx4;

// round-to-nearest-even f32 -> bf16 (inputs are finite Gaussians; no NaN handling needed)
static __device__ __forceinline__ short f2bf(float f) {
  union { float f; unsigned u; } x; x.f = f;
  unsigned r = (x.u + 0x7fffu + ((x.u >> 16) & 1u)) >> 16;
  return (short)r;
}

__global__ void conv_w_kernel(const float* __restrict__ W, short* __restrict__ Wb) {
  int i = blockIdx.x * 256 + threadIdx.x;
  if (i < ODIM * KDIM) Wb[i] = f2bf(W[i]);
}

// scan1: one node per thread. Sum the node's 8 per-XCD counts, pad total to
// multiple of 4 (spmm reads int4 pairs), block-level exclusive scan.
__global__ void scan1_kernel(const unsigned* __restrict__ counts, int* __restrict__ chunkExcl,
                             int* __restrict__ blockSums) {
  __shared__ int s[256];
  int t = threadIdx.x;
  int n = blockIdx.x * 256 + t;
  int sum = 0;
  if (n < NNODES) {
    int s0 = 0;
#pragma unroll
    for (int x = 0; x < NXCD; x++) s0 += (int)counts[(size_t)x * NNODES + n];
    sum = (s0 + 3) & ~3;  // pad segment to multiple of 4 records
  }
  s[t] = sum;
  __syncthreads();
  for (int o = 1; o < 256; o <<= 1) {
    int add = (t >= o) ? s[t - o] : 0;
    __syncthreads();
    s[t] += add;
    __syncthreads();
  }
  if (n < NNODES) chunkExcl[n] = s[t] - sum;
  if (t == 255) blockSums[blockIdx.x] = s[255];
}

// single-block exclusive scan of the 391 chunk totals; writes offsets[NNODES] = total
__global__ void scan2_kernel(const int* __restrict__ blockSums, int* __restrict__ blockBase,
                             int* __restrict__ offsets) {
  __shared__ int s[512];
  int t = threadIdx.x;
  int v = (t < NB_SCAN) ? blockSums[t] : 0;
  s[t] = v;
  __syncthreads();
  for (int o = 1; o < 512; o <<= 1) {
    int add = (t >= o) ? s[t - o] : 0;
    __syncthreads();
    s[t] += add;
    __syncthreads();
  }
  if (t < NB_SCAN) blockBase[t] = s[t] - v;
  if (t == 511) offsets[NNODES] = s[511];
}

// scan3: per node, write offsets[n] (segment start, multiple of 4) and convert the
// node's 8 per-XCD COUNTS in place into ABSOLUTE per-XCD base positions.
__global__ void scan3_kernel(const int* __restrict__ chunkExcl, const int* __restrict__ blockBase,
                             unsigned* __restrict__ counts, int* __restrict__ offsets) {
  int n = blockIdx.x * 256 + threadIdx.x;
  if (n >= NNODES) return;
  int run = chunkExcl[n] + blockBase[n >> 8];
  offsets[n] = run;
#pragma unroll
  for (int x = 0; x < NXCD; x++) {
    int c = (int)counts[(size_t)x * NNODES + n];
    counts[(size_t)x * NNODES + n] = (unsigned)run;
    run += c;
  }
}

// Atomic-free placement: pos = xcdBase[xcc][row] + local_rank. The 3.2 MB base
// array is L2-resident random read; the scattered 8 B store has no RMW dependency.
__global__ void place_kernel(const int* __restrict__ rows, const int* __restrict__ cols,
                             const float* __restrict__ vals,
                             const unsigned short* __restrict__ rank,
                             const unsigned* __restrict__ sbase, int2* __restrict__ edges) {
  int i = blockIdx.x * 256 + threadIdx.x;
#pragma unroll
  for (int j = 0; j < 4; j++) {
    int e = i + j * ESTRIDE;
    if (e < NEDGES) {
      int r = rows[e];
      unsigned rk = rank[e];
      int p = (int)sbase[(size_t)(rk >> 8) * NNODES + r] + (int)(rk & 255u);
      int2 rec;
      rec.x = cols[e];
      rec.y = __float_as_int(vals[e]);
      edges[p] = rec;
    }
  }
}

// Fused: blocks [0, RANK_BLOCKS) run the histogram+rank (FIRST, so the critical-
// path atomics start before CUs fill with gemm work); blocks [RANK_BLOCKS, +GEMM)
// compute packed bf16 H.
//
// rank path: counts is replicated per-XCD (8 x 400 KB, each copy fits its XCD's
// 4 MB L2). The wave reads its XCD via s_getreg(HW_REG_XCC_ID) and increments its
// own copy with a RELAXED WORKGROUP-SCOPE atomic -> global_atomic_add WITHOUT
// cross-XCD coherence, executed in the local TCC. Atomicity is only needed among
// waves on the same XCD (they share that L2); indexing by the executing wave's
// xcc guarantees that. Cross-kernel visibility = dispatch-end L2 writeback (same
// mechanism all plain stores here already rely on). This removes the per-atomic
// memory-side RMW (the ~43 MB of unexplained WRITE_SIZE).
//
// gemm: 64 rows/block, 16 rows/wave, all 8 n-tiles per wave. K-loop fully
// unrolled, 2-deep register double-buffer on the X loads (round-0 structure).
// D layout: col = t*16 + (lane&15), row = quad*4 + reg  [m89 layout]
// H stored PACKED: u32 word j = (bf16 col j) | (bf16 col j+64)<<16; cols j and
// j+64 live in the same lane (acc[t], acc[t+4]) -> lane-local pack, 4 B stores.
__global__ __launch_bounds__(256) void gemm_rank_kernel(
    const float* __restrict__ X, const short* __restrict__ Wb,
    const float* __restrict__ bias, unsigned* __restrict__ H2,
    const int* __restrict__ rows, unsigned* __restrict__ counts,
    unsigned short* __restrict__ rank) {
  if (blockIdx.x < RANK_BLOCKS) {
    // ---- rank path: 4 independent XCD-local atomic chains per thread ----
    unsigned xcc;
    asm("s_getreg_b32 %0, hwreg(HW_REG_XCC_ID)" : "=s"(xcc));
    xcc &= 7u;
    unsigned* cbase = counts + (size_t)xcc * NNODES;
    int i = blockIdx.x * 256 + threadIdx.x;
#pragma unroll
    for (int j = 0; j < 4; j++) {
      int e = i + j * ESTRIDE;
      if (e < NEDGES) {
        int r = rows[e];
        unsigned old = __hip_atomic_fetch_add(&cbase[r], 1u, __ATOMIC_RELAXED,
                                              __HIP_MEMORY_SCOPE_WORKGROUP);
        rank[e] = (unsigned short)((xcc << 8) | old);  // per-XCD deg < 256 (max deg ~45)
      }
    }
    return;
  }
  // ---- gemm path ----
  const int gb = blockIdx.x - RANK_BLOCKS;
  const int lane = threadIdx.x & 63;
  const int wave = threadIdx.x >> 6;
  const int l16 = lane & 15;
  const int quad = lane >> 4;
  const int rowBase = gb * 64 + wave * 16;
  const int arow = rowBase + l16;
  const bool inb = arow < NNODES;
  const float4 zf4 = {0.f, 0.f, 0.f, 0.f};
  // lane's X stream: row arow, starting at k = quad*8; k-step stride = 32 floats
  const float4* xp = (const float4*)(X + (size_t)(inb ? arow : 0) * KDIM + quad * 8);

  floatx4 acc[8];
#pragma unroll
  for (int t = 0; t < 8; t++) acc[t] = (floatx4){0.f, 0.f, 0.f, 0.f};

  float4 c0 = inb ? xp[0] : zf4;
  float4 c1 = inb ? xp[1] : zf4;
#pragma unroll
  for (int k0 = 0; k0 < 8; k0++) {
    float4 n0, n1;
    if (k0 < 7) {
      n0 = inb ? xp[(k0 + 1) * 8] : zf4;
      n1 = inb ? xp[(k0 + 1) * 8 + 1] : zf4;
    }
    short8 a;
    a[0] = f2bf(c0.x); a[1] = f2bf(c0.y); a[2] = f2bf(c0.z); a[3] = f2bf(c0.w);
    a[4] = f2bf(c1.x); a[5] = f2bf(c1.y); a[6] = f2bf(c1.z); a[7] = f2bf(c1.w);
    const short* bp = Wb + k0 * 32 + quad * 8;
#pragma unroll
    for (int t = 0; t < 8; t++) {
      short8 b = *(const short8*)(bp + (size_t)(t * 16 + l16) * KDIM);
      acc[t] = __builtin_amdgcn_mfma_f32_16x16x32_bf16(a, b, acc[t], 0, 0, 0);
    }
    if (k0 < 7) { c0 = n0; c1 = n1; }
  }

#pragma unroll
  for (int t = 0; t < 4; t++) {
    const int cl = t * 16 + l16;
    const float blo = bias[cl];
    const float bhi = bias[cl + 64];
#pragma unroll
    for (int r = 0; r < 4; r++) {
      const int row = rowBase + quad * 4 + r;
      if (row < NNODES) {
        unsigned lo = (unsigned short)f2bf(acc[t][r] + blo);
        unsigned hi = (unsigned short)f2bf(acc[t + 4][r] + bhi);
        H2[(size_t)row * 64 + cl] = lo | (hi << 16);
      }
    }
  }
}

// One wave per output row. Lane owns channels {lane, lane+64} (one uint = packed
// bf16 pair per gathered H row -> 256 B coalesced per edge). Segments are padded
// to a multiple of 4 records (pad = {col 0, val 0}) -> no tail loop.
__global__ __launch_bounds__(256) void spmm_kernel(const int* __restrict__ offsets,
                                                   const int2* __restrict__ edges,
                                                   const unsigned* __restrict__ H2,
                                                   float* __restrict__ out) {
  const int lane = threadIdx.x & 63;
  const int row = blockIdx.x * 4 + (threadIdx.x >> 6);
  if (row >= NNODES) return;
  const int s = offsets[row];      // multiple of 4
  const int e = offsets[row + 1];
  float ax = 0.f, ay = 0.f;
  for (int i = s; i < e; i += 4) {
    const int4 p01 = *(const int4*)(edges + i);      // 16 B aligned (s % 4 == 0)
    const int4 p23 = *(const int4*)(edges + i + 2);
    const unsigned h0 = H2[(size_t)p01.x * 64 + lane];
    const unsigned h1 = H2[(size_t)p01.z * 64 + lane];
    const unsigned h2 = H2[(size_t)p23.x * 64 + lane];
    const unsigned h3 = H2[(size_t)p23.z * 64 + lane];
    const float v0 = __int_as_float(p01.y);
    const float v1 = __int_as_float(p01.w);
    const float v2 = __int_as_float(p23.y);
    const float v3 = __int_as_float(p23.w);
    ax += v0 * __uint_as_float(h0 << 16);            // col = lane
    ay += v0 * __uint_as_float(h0 & 0xffff0000u);    // col = lane + 64
    ax += v1 * __uint_as_float(h1 << 16);
    ay += v1 * __uint_as_float(h1 & 0xffff0000u);
    ax += v2 * __uint_as_float(h2 << 16);
    ay += v2 * __uint_as_float(h2 & 0xffff0000u);
    ax += v3 * __uint_as_float(h3 << 16);
    ay += v3 * __uint_as_float(h3 & 0xffff0000u);
  }
  out[(size_t)row * 128 + lane] = ax;
  out[(size_t)row * 128 + 64 + lane] = ay;
}

extern "C" void kernel_launch(void* const* d_in, const int* in_sizes, int n_in,
                              void* d_out, int out_size, void* d_ws, size_t ws_size,
                              hipStream_t stream) {
  const float* X = (const float*)d_in[0];
  const int* erow = (const int*)d_in[1];
  const int* ecol = (const int*)d_in[2];
  const float* eval = (const float*)d_in[3];
  const float* W = (const float*)d_in[4];
  const float* bias = (const float*)d_in[5];
  float* out = (float*)d_out;

  char* ws = (char*)d_ws;
  size_t off = 0;
  auto alloc = [&](size_t bytes) -> char* {
    char* p = ws + off;
    off += (bytes + 255) & ~(size_t)255;
    return p;
  };
  unsigned* Hb = (unsigned*)alloc((size_t)NNODES * 64 * 4);                // 25.6 MB packed
  short* Wb = (short*)alloc((size_t)ODIM * KDIM * 2);                      // 64 KB
  unsigned* counts = (unsigned*)alloc((size_t)NXCD * NNODES * 4);          // 3.2 MB (-> bases)
  int* chunkExcl = (int*)alloc((size_t)NNODES * 4);
  int* offsets = (int*)alloc((size_t)(NNODES + 1) * 4);
  int* blockSums = (int*)alloc((size_t)NB_SCAN * 4);
  int* blockBase = (int*)alloc((size_t)NB_SCAN * 4);
  unsigned short* rank = (unsigned short*)alloc((size_t)NEDGES * 2);  // 3.2 MB
  int2* edges = (int2*)alloc((size_t)EDGE_CAP * 8);  // 15.2 MB, padded CSR records

  hipMemsetAsync(counts, 0, (size_t)NXCD * NNODES * 4, stream);
  hipMemsetAsync(edges, 0, (size_t)EDGE_CAP * 8, stream);  // pad records = {col 0, val 0}
  conv_w_kernel<<<(ODIM * KDIM + 255) / 256, 256, 0, stream>>>(W, Wb);
  gemm_rank_kernel<<<RANK_BLOCKS + GEMM_BLOCKS, 256, 0, stream>>>(X, Wb, bias, Hb,
                                                                  erow, counts, rank);
  scan1_kernel<<<NB_SCAN, 256, 0, stream>>>(counts, chunkExcl, blockSums);
  scan2_kernel<<<1, 512, 0, stream>>>(blockSums, blockBase, offsets);
  scan3_kernel<<<NB_SCAN, 256, 0, stream>>>(chunkExcl, blockBase, counts, offsets);
  place_kernel<<<(ESTRIDE + 255) / 256, 256, 0, stream>>>(erow, ecol, eval, rank, counts, edges);
  spmm_kernel<<<(NNODES + 3) / 4, 256, 0, stream>>>(offsets, edges, (const unsigned*)Hb, out);
}